// Round 11
// baseline (170.175 us; speedup 1.0000x reference)
//
#include <hip/hip_runtime.h>

typedef unsigned short ushort_t;
typedef __attribute__((ext_vector_type(8)))  short  short8;
typedef __attribute__((ext_vector_type(4)))  short  short4v;
typedef __attribute__((ext_vector_type(4)))  float  float4v;
typedef __attribute__((ext_vector_type(4)))  int    int4v;

#define N_NODES 4096
#define NHEADS  4
#define DK      128
#define ODIM    512
#define KDIM    512

__device__ __forceinline__ float bf2f(ushort_t u) {
    return __uint_as_float(((unsigned)u) << 16);
}
__device__ __forceinline__ ushort_t f2bf_rne(float f) {
    unsigned u = __float_as_uint(f);
    u += 0x7fffu + ((u >> 16) & 1u);
    return (ushort_t)(u >> 16);
}

// ---------------------------------------------------------------------------
// Kernel 1 (fused): mask bit-pack + dtype flag + W transpose + sl/sr zeroing.
// ---------------------------------------------------------------------------
__global__ __launch_bounds__(256) void pack_mask_k(const int* __restrict__ A,
                                                   unsigned long long* __restrict__ P,
                                                   const ushort_t* __restrict__ Hraw,
                                                   int* __restrict__ flag,
                                                   const void* __restrict__ W,
                                                   ushort_t* __restrict__ WT,
                                                   float* __restrict__ sl,
                                                   float* __restrict__ sr)
{
    __shared__ ushort_t lt[64][72];
    __shared__ int dcnt[4];
    const int tid = threadIdx.x;
    const int bx  = blockIdx.x;

    if (bx == 0 && tid < 64) {
        const int lane = tid;
        int cnt = 0;
        #pragma unroll
        for (int s = 0; s < 16; ++s) {
            ushort_t v = Hraw[(lane * 16 + s) * 2];
            int e = (v >> 7) & 0xFF;
            cnt += (((e >= 90) && (e <= 140)) || (v == 0)) ? 1 : 0;
        }
        #pragma unroll
        for (int off = 32; off; off >>= 1) cnt += __shfl_down(cnt, off);
        if (lane == 0) *flag = (cnt < 768) ? 1 : 0;
    }

    // ---- mask pack (all blocks): 4 int4 per thread ----
    {
        const int lane = tid & 63;
        #pragma unroll
        for (int kk = 0; kk < 4; ++kk) {
            const int flat4 = (bx * 4 + kk) * 256 + tid;   // index in units of int4
            const int row   = flat4 >> 10;                 // (flat4*4) >> 12
            const int col0  = (flat4 << 2) & 4095;
            const int4v a   = ((const int4v*)A)[flat4];
            unsigned nib = 0;
            #pragma unroll
            for (int j = 0; j < 4; ++j)
                nib |= ((a[j] != 0) || (row == col0 + j)) ? (1u << j) : 0u;
            unsigned long long v = (unsigned long long)nib << ((lane & 15) * 4);
            v |= __shfl_xor(v, 1);
            v |= __shfl_xor(v, 2);
            v |= __shfl_xor(v, 4);
            v |= __shfl_xor(v, 8);
            if ((lane & 15) == 0) P[flat4 >> 4] = v;
        }
    }

    // ---- zero sl/sr (blocks 64..95): 8192 threads x one float4 ----
    if (bx >= 64 && bx < 96) {
        const int idx = (bx - 64) * 256 + tid;        // 0..8191
        float4v z;
        #pragma unroll
        for (int e = 0; e < 4; ++e) z[e] = 0.f;
        if (idx < 4096) ((float4v*)sl)[idx] = z;
        else            ((float4v*)sr)[idx - 4096] = z;
    }

    // ---- W transpose (blocks 0..63) ----
    if (bx < 64) {
        // block-local dtype detection (same 1024 samples as the global flag)
        int cnt = 0;
        #pragma unroll
        for (int s = 0; s < 4; ++s) {
            ushort_t v = Hraw[(tid * 4 + s) * 2];
            int e = (v >> 7) & 0xFF;
            cnt += (((e >= 90) && (e <= 140)) || (v == 0)) ? 1 : 0;
        }
        #pragma unroll
        for (int off = 32; off; off >>= 1) cnt += __shfl_down(cnt, off);
        if ((tid & 63) == 0) dcnt[tid >> 6] = cnt;
        __syncthreads();
        const int f32 = (dcnt[0] + dcnt[1] + dcnt[2] + dcnt[3]) < 768;

        const int ti = bx >> 3, tj = bx & 7;
        const int r = tid >> 2, c2 = tid & 3;
        const size_t eo = (size_t)(ti * 64 + r) * KDIM + tj * 64 + c2 * 16;
        if (f32) {
            const float4v* src = (const float4v*)((const float*)W + eo);
            float4v f0 = src[0], f1 = src[1], f2 = src[2], f3 = src[3];
            #pragma unroll
            for (int e = 0; e < 4; ++e) {
                lt[r][c2 * 16 +  0 + e] = f2bf_rne(f0[e]);
                lt[r][c2 * 16 +  4 + e] = f2bf_rne(f1[e]);
                lt[r][c2 * 16 +  8 + e] = f2bf_rne(f2[e]);
                lt[r][c2 * 16 + 12 + e] = f2bf_rne(f3[e]);
            }
        } else {
            const short8* src = (const short8*)((const ushort_t*)W + eo);
            short8 v0 = src[0];
            short8 v1 = src[1];
            *(short8*)&lt[r][c2 * 16]     = v0;
            *(short8*)&lt[r][c2 * 16 + 8] = v1;
        }
        __syncthreads();
        #pragma unroll
        for (int itr = 0; itr < 2; ++itr) {
            int idx = itr * 256 + tid;
            int n = idx >> 3, c = idx & 7;
            short8 vv;
            #pragma unroll
            for (int e = 0; e < 8; ++e) vv[e] = (short)lt[c * 8 + e][n];
            *(short8*)(WT + (size_t)(tj * 64 + n) * KDIM + ti * 64 + c * 8) = vv;
        }
    }
}

// ---------------------------------------------------------------------------
// Kernel 2 v19 (unchanged): WhT = (H @ W)^T with LDS-staged B panel + fused
// slsr partials.
// ---------------------------------------------------------------------------
__global__ __launch_bounds__(256) void gemm_wht_dual_k(const void* __restrict__ H,
                                                       const ushort_t* __restrict__ WT,
                                                       ushort_t* __restrict__ WhT,
                                                       const int* __restrict__ flag,
                                                       const void* __restrict__ al,
                                                       const void* __restrict__ ar,
                                                       float* __restrict__ sl,
                                                       float* __restrict__ sr)
{
    __shared__ ushort_t Bs[64 * KDIM];   // 64 KB staged B panel (slot-swizzled)
    __shared__ ushort_t lt[64][72];
    const int f32 = *flag;
    const int tid  = threadIdx.x;
    const int lane = tid & 63;
    const int wid  = tid >> 6;
    const int quad = lane >> 4;
    const int l15  = lane & 15;
    const int bm = blockIdx.x & 63, bn = blockIdx.x >> 6;
    const int i0 = bm * 64, n0 = bn * 64;

    // ---- stage B panel: wave wid stages rows wid*16 .. +15, 1 call/row ----
    #pragma unroll
    for (int rr = 0; rr < 16; ++rr) {
        const int n = wid * 16 + rr;
        const ushort_t* src = WT + (size_t)(n0 + n) * KDIM + (size_t)((lane ^ (n & 3)) * 8);
        __builtin_amdgcn_global_load_lds(
            (const __attribute__((address_space(1))) void*)src,
            (__attribute__((address_space(3))) void*)(Bs + n * KDIM), 16, 0, 0);
    }
    asm volatile("s_waitcnt vmcnt(0)" ::: "memory");
    __syncthreads();

    const size_t aoff = (size_t)(i0 + wid * 16 + l15) * KDIM + quad * 8;

    float4v acc0, acc1, acc2, acc3;
    #pragma unroll
    for (int e = 0; e < 4; ++e) { acc0[e] = 0.f; acc1[e] = 0.f; acc2[e] = 0.f; acc3[e] = 0.f; }

    const int sx = l15 & 3;   // read-slot XOR (matches stage pre-swizzle)

    #pragma unroll 4
    for (int k8 = 0; k8 < 64; k8 += 4) {
        short8 a;
        if (f32) {
            const float4v* fp = (const float4v*)((const float*)H + aoff + (size_t)k8 * 8);
            float4v x0 = fp[0], x1 = fp[1];
            #pragma unroll
            for (int e = 0; e < 4; ++e) {
                a[e]     = (short)f2bf_rne(x0[e]);
                a[4 + e] = (short)f2bf_rne(x1[e]);
            }
        } else {
            a = *(const short8*)((const ushort_t*)H + aoff + (size_t)k8 * 8);
        }
        const int s = (quad + k8) ^ sx;
        short8 b0 = *(const short8*)(Bs + ( 0 + l15) * KDIM + s * 8);
        short8 b1 = *(const short8*)(Bs + (16 + l15) * KDIM + s * 8);
        short8 b2 = *(const short8*)(Bs + (32 + l15) * KDIM + s * 8);
        short8 b3 = *(const short8*)(Bs + (48 + l15) * KDIM + s * 8);
        acc0 = __builtin_amdgcn_mfma_f32_16x16x32_bf16(a, b0, acc0, 0, 0, 0);
        acc1 = __builtin_amdgcn_mfma_f32_16x16x32_bf16(a, b1, acc1, 0, 0, 0);
        acc2 = __builtin_amdgcn_mfma_f32_16x16x32_bf16(a, b2, acc2, 0, 0, 0);
        acc3 = __builtin_amdgcn_mfma_f32_16x16x32_bf16(a, b3, acc3, 0, 0, 0);
    }

    #pragma unroll
    for (int r = 0; r < 4; ++r) {
        int m = wid * 16 + quad * 4 + r;
        lt[ 0 + l15][m] = f2bf_rne(acc0[r]);
        lt[16 + l15][m] = f2bf_rne(acc1[r]);
        lt[32 + l15][m] = f2bf_rne(acc2[r]);
        lt[48 + l15][m] = f2bf_rne(acc3[r]);
    }
    __syncthreads();
    #pragma unroll
    for (int itr = 0; itr < 2; ++itr) {
        int idx = itr * 256 + tid;
        int n = idx >> 3, c = idx & 7;
        short8 v = *(const short8*)&lt[n][c * 8];
        *(short8*)(WhT + (size_t)(n0 + n) * N_NODES + i0 + c * 8) = v;
    }

    // ---- fused slsr partials over this block's 64 d-values ----
    {
        const int h2 = n0 >> 7;          // head
        const int d0 = n0 & 127;         // d offset within head
        const int m  = tid >> 2;         // output row = i0 + m
        const int part = tid & 3;
        float psl = 0.f, psr = 0.f;
        #pragma unroll
        for (int k = 0; k < 16; ++k) {
            int n = part * 16 + k;
            float wv = bf2f(lt[n][m]);
            float av = f32 ? ((const float*)al)[h2 * DK + d0 + n]
                           : bf2f(((const ushort_t*)al)[h2 * DK + d0 + n]);
            float bv = f32 ? ((const float*)ar)[h2 * DK + d0 + n]
                           : bf2f(((const ushort_t*)ar)[h2 * DK + d0 + n]);
            psl += wv * av;
            psr += wv * bv;
        }
        psl += __shfl_down(psl, 2); psl += __shfl_down(psl, 1);
        psr += __shfl_down(psr, 2); psr += __shfl_down(psr, 1);
        if (part == 0) {
            atomicAdd(&sl[h2 * N_NODES + i0 + m], psl);
            atomicAdd(&sr[h2 * N_NODES + i0 + m], psr);
        }
    }
}

// ---------------------------------------------------------------------------
// Kernel 3 v21: 2 row-groups x 2 row-sets — halve LDS V-read traffic.
// v20 pipe arithmetic: LDS reads = 16 waves x 16KB x 16 windows = 4MB/CU
// (+srs+DMA) ~= 22us of the 41.8us kernel — V-read amplification = 4
// row-groups.  v21: waves = (rq 0..1, 32 rows) x (js 0..7, 32j streams);
// per window each wave reads 8 B-fragments (one 32j chunk) and issues 16
// MFMAs (two 16-row sets SHARE every B read) -> amplification 2, srs reads
// halved, VALU unchanged (2 pf: same srj, two slv), MFMA count unchanged.
// acc 2x8 (64 VGPR, ~106 total <= 128 cap; spill signal = WRITE_SIZE jump).
// DMA staging, window size (256j x 128d, 2 buffers, 1 syncthreads/window),
// mask register-prefetch, and the slot involution slot = p ^ (d&31) are
// v20's verified ones, unchanged.  Epilogue: 3-stage js-tree (8->4->2->1)
// in the dead vbuf region.
// ---------------------------------------------------------------------------
__global__ __launch_bounds__(1024, 4) void attn_full_k(const ushort_t* __restrict__ WhT,
                                                       const unsigned* __restrict__ Apack,
                                                       const float* __restrict__ sl,
                                                       const float* __restrict__ sr,
                                                       void* __restrict__ out,
                                                       const int* __restrict__ flag)
{
    __shared__ char smem[147456] __attribute__((aligned(16)));
    ushort_t* vbuf = (ushort_t*)smem;                 // 2 x 64 KB windows
    float*    srs  = (float*)(smem + 131072);         // 4096 f32, 16 KB

    const int f32  = *flag;
    const int tid  = threadIdx.x;
    const int lane = tid & 63;
    const int wid  = tid >> 6;               // 0..15
    const int rq   = wid & 1;                // row half: rows rq*32..+31
    const int js   = wid >> 1;               // j substream 0..7 (32j of each window)
    const int quad = lane >> 4;
    const int l15  = lane & 15;
    const int bx   = blockIdx.x;
    const int h    = bx & 3;                 // head
    const int i0   = (bx >> 2) << 6;         // 64-row tile

    const float C1 = 1.44269504f;             // log2(e)

    for (int j = tid; j < 4096; j += 1024) srs[j] = sr[h * N_NODES + j] * C1;
    const int row_lo = rq * 32 + l15;
    const int row_hi = rq * 32 + 16 + l15;
    const float slv0 = sl[h * N_NODES + i0 + row_lo] * C1;
    const float slv1 = sl[h * N_NODES + i0 + row_hi] * C1;
    const unsigned* mlo = Apack + (size_t)(i0 + row_lo) * 128;
    const unsigned* mhi = Apack + (size_t)(i0 + row_hi) * 128;
    __syncthreads();    // srs visible

    float4v acc[2][8];
    #pragma unroll
    for (int m = 0; m < 2; ++m)
        #pragma unroll
        for (int nt = 0; nt < 8; ++nt)
            #pragma unroll
            for (int e = 0; e < 4; ++e) acc[m][nt][e] = 0.f;
    float4v accden0, accden1;
    #pragma unroll
    for (int e = 0; e < 4; ++e) { accden0[e] = 0.f; accden1[e] = 0.f; }

    short8 ones;
    #pragma unroll
    for (int e = 0; e < 8; ++e) ones[e] = (short)0x3F80;   // bf16 1.0

    // DMA: window = 256j x 128d (64 KB), row = 512 B (32 slots of 16 B).
    // Wave wid stages d-rows [wid*8, +8) via 4 calls of 2 rows.
    // Slot s of row d holds global j-chunk s ^ (d&31)  (v20's involution).
    const int rrow  = lane >> 5;             // 0..1
    const int s32   = lane & 31;
    const int dbase = wid * 8;

    #define DMA_WIN(BUF, W)                                                            \
        { _Pragma("unroll")                                                            \
          for (int q_ = 0; q_ < 4; ++q_) {                                             \
            const int d_  = dbase + q_ * 2 + rrow;                                     \
            const int ch_ = s32 ^ (d_ & 31);                                           \
            const ushort_t* g_ = WhT + (size_t)(h * DK + d_) * N_NODES                 \
                                      + (size_t)(W) * 256 + (size_t)ch_ * 8;           \
            __builtin_amdgcn_global_load_lds(                                          \
                (const __attribute__((address_space(1))) void*)g_,                     \
                (__attribute__((address_space(3))) void*)(vbuf + (BUF) * 32768         \
                                                         + wid * 2048 + q_ * 512),     \
                16, 0, 0);                                                             \
          } }

    unsigned wa0 = mlo[js];
    unsigned wa1 = mhi[js];
    DMA_WIN(0, 0)

    #pragma unroll 1
    for (int w = 0; w < 16; ++w) {
        __syncthreads();                     // drains vmcnt: window w + masks landed
        unsigned wa0n = wa0, wa1n = wa1;
        if (w < 15) {
            wa0n = mlo[(w + 1) * 8 + js];
            wa1n = mhi[(w + 1) * 8 + js];
            DMA_WIN((w + 1) & 1, w + 1)
        }

        const float4v a0 = *(const float4v*)&srs[w * 256 + js * 32 + quad * 8];
        const float4v a1 = *(const float4v*)&srs[w * 256 + js * 32 + quad * 8 + 4];

        short8 pf0, pf1;
        #pragma unroll
        for (int jj = 0; jj < 8; ++jj) {
            const int bit = quad * 8 + jj;
            const float srj = (jj < 4) ? a0[jj] : a1[jj - 4];   // *C1
            float x = slv0 + srj;
            float t = fmaxf(x, x * 0.2f);
            t = ((wa0 >> bit) & 1u) ? t : -1e30f;
            pf0[jj] = (short)(ushort_t)(__float_as_uint(__builtin_amdgcn_exp2f(t)) >> 16);
            float y = slv1 + srj;
            float u = fmaxf(y, y * 0.2f);
            u = ((wa1 >> bit) & 1u) ? u : -1e30f;
            pf1[jj] = (short)(ushort_t)(__float_as_uint(__builtin_amdgcn_exp2f(u)) >> 16);
        }

        const ushort_t* vB = vbuf + (w & 1) * 32768;
        __builtin_amdgcn_s_setprio(1);
        #pragma unroll
        for (int nt = 0; nt < 8; ++nt) {
            const int roff = (nt * 16 + l15) * 256;             // ushorts
            const int dlow = (nt & 1) * 16 + l15;               // d&31 of this row
            const int slot = (js * 4 + quad) ^ dlow;
            short8 bv = *(const short8*)(vB + roff + slot * 8);
            acc[0][nt] = __builtin_amdgcn_mfma_f32_16x16x32_bf16(pf0, bv, acc[0][nt], 0, 0, 0);
            acc[1][nt] = __builtin_amdgcn_mfma_f32_16x16x32_bf16(pf1, bv, acc[1][nt], 0, 0, 0);
        }
        accden0 = __builtin_amdgcn_mfma_f32_16x16x32_bf16(pf0, ones, accden0, 0, 0, 0);
        accden1 = __builtin_amdgcn_mfma_f32_16x16x32_bf16(pf1, ones, accden1, 0, 0, 0);
        __builtin_amdgcn_s_setprio(0);

        wa0 = wa0n; wa1 = wa1n;
    }
    #undef DMA_WIN

    // ---- epilogue: js-tree reduction 8->4->2->1, normalize, elu, store ----
    float* red  = (float*)smem;                       // 8 regions x 16 KB (stage A)
    float* lsum = (float*)(smem + 131072);            // 7 js x 64 rows f32
    __syncthreads();                                   // all DMAs drained; reads done

    if (js != 0 && l15 == 0) {
        #pragma unroll
        for (int r = 0; r < 4; ++r) {
            lsum[(js - 1) * 64 + rq * 32 + quad * 4 + r]      = accden0[r];
            lsum[(js - 1) * 64 + rq * 32 + 16 + quad * 4 + r] = accden1[r];
        }
    }
    #define RED_WRITE(IDX)                                                             \
        {   float* rp_ = red + (size_t)(IDX) * 4096;                                   \
            _Pragma("unroll")                                                          \
            for (int m = 0; m < 2; ++m)                                                \
              _Pragma("unroll")                                                        \
              for (int nt = 0; nt < 8; ++nt)                                           \
                _Pragma("unroll")                                                      \
                for (int r = 0; r < 4; ++r)                                            \
                    rp_[(m * 16 + quad * 4 + r) * 128 + nt * 16 + l15] = acc[m][nt][r]; }
    #define RED_ADD(IDX)                                                               \
        {   float* rp_ = red + (size_t)(IDX) * 4096;                                   \
            _Pragma("unroll")                                                          \
            for (int m = 0; m < 2; ++m)                                                \
              _Pragma("unroll")                                                        \
              for (int nt = 0; nt < 8; ++nt)                                           \
                _Pragma("unroll")                                                      \
                for (int r = 0; r < 4; ++r)                                            \
                    acc[m][nt][r] += rp_[(m * 16 + quad * 4 + r) * 128 + nt * 16 + l15]; }

    if (js >= 4) RED_WRITE((js - 4) * 2 + rq)
    __syncthreads();
    if (js < 4)  RED_ADD(js * 2 + rq)
    __syncthreads();
    if (js == 2 || js == 3) RED_WRITE((js - 2) * 2 + rq)
    __syncthreads();
    if (js < 2)  RED_ADD(js * 2 + rq)
    __syncthreads();
    if (js == 1) RED_WRITE(rq)
    __syncthreads();
    if (js == 0) {
        RED_ADD(rq)
        #pragma unroll
        for (int m = 0; m < 2; ++m) {
            float rinv[4];
            #pragma unroll
            for (int r = 0; r < 4; ++r) {
                const int row = rq * 32 + m * 16 + quad * 4 + r;
                float den = (m == 0) ? accden0[r] : accden1[r];
                #pragma unroll
                for (int q = 1; q < 8; ++q) den += lsum[(q - 1) * 64 + row];
                rinv[r] = 1.0f / fmaxf(den, 1e-37f);
            }
            #pragma unroll
            for (int nt = 0; nt < 8; ++nt)
                #pragma unroll
                for (int r = 0; r < 4; ++r) {
                    float v = acc[m][nt][r] * rinv[r];
                    float e = __builtin_amdgcn_exp2f(v * C1) - 1.0f;
                    float o = (v > 0.f) ? v : e;
                    const size_t oidx = (size_t)(i0 + rq * 32 + m * 16 + quad * 4 + r) * ODIM
                                      + h * DK + nt * 16 + l15;
                    if (f32) ((float*)out)[oidx] = o;
                    else     ((ushort_t*)out)[oidx] = f2bf_rne(o);
                }
        }
    }
    #undef RED_WRITE
    #undef RED_ADD
}

// ---------------------------------------------------------------------------
extern "C" void kernel_launch(void* const* d_in, const int* in_sizes, int n_in,
                              void* d_out, int out_size, void* d_ws, size_t ws_size,
                              hipStream_t stream)
{
    const void* H  = d_in[0];
    const int*  A  = (const int*)d_in[1];
    const void* W  = d_in[2];
    const void* al = d_in[3];
    const void* ar = d_in[4];

    if (ws_size < (7u << 20)) return;

    char* ws = (char*)d_ws;
    ushort_t* WhT   = (ushort_t*)ws;                                    // 4 MB
    unsigned long long* Apack = (unsigned long long*)(ws + (4u << 20)); // 2 MB
    ushort_t* WT    = (ushort_t*)(ws + (6u << 20));                     // 512 KB
    float*    sl    = (float*)(ws + (6u << 20) + (512u << 10));         // 64 KB
    float*    sr    = (float*)(ws + (6u << 20) + (576u << 10));         // 64 KB
    int*      flag  = (int*)(ws + (6u << 20) + (640u << 10));           // 4 B

    pack_mask_k    <<<4096,  256, 0, stream>>>(A, Apack, (const ushort_t*)H, flag,
                                               W, WT, sl, sr);
    gemm_wht_dual_k<<<512,   256, 0, stream>>>(H, WT, WhT, flag, al, ar, sl, sr);
    attn_full_k    <<<256,  1024, 0, stream>>>(WhT, (const unsigned*)Apack, sl, sr,
                                               (void*)d_out, flag);
}

// Round 12
// 158.962 us; speedup vs baseline: 1.0705x; 1.0705x over previous
//
#include <hip/hip_runtime.h>

typedef unsigned short ushort_t;
typedef __attribute__((ext_vector_type(8)))  short  short8;
typedef __attribute__((ext_vector_type(4)))  short  short4v;
typedef __attribute__((ext_vector_type(4)))  float  float4v;
typedef __attribute__((ext_vector_type(4)))  int    int4v;

#define N_NODES 4096
#define NHEADS  4
#define DK      128
#define ODIM    512
#define KDIM    512

__device__ __forceinline__ float bf2f(ushort_t u) {
    return __uint_as_float(((unsigned)u) << 16);
}
__device__ __forceinline__ ushort_t f2bf_rne(float f) {
    unsigned u = __float_as_uint(f);
    u += 0x7fffu + ((u >> 16) & 1u);
    return (ushort_t)(u >> 16);
}

// ---------------------------------------------------------------------------
// Kernel 1 (fused): mask bit-pack + dtype flag + W transpose + sl/sr zeroing.
// ---------------------------------------------------------------------------
__global__ __launch_bounds__(256) void pack_mask_k(const int* __restrict__ A,
                                                   unsigned long long* __restrict__ P,
                                                   const ushort_t* __restrict__ Hraw,
                                                   int* __restrict__ flag,
                                                   const void* __restrict__ W,
                                                   ushort_t* __restrict__ WT,
                                                   float* __restrict__ sl,
                                                   float* __restrict__ sr)
{
    __shared__ ushort_t lt[64][72];
    __shared__ int dcnt[4];
    const int tid = threadIdx.x;
    const int bx  = blockIdx.x;

    if (bx == 0 && tid < 64) {
        const int lane = tid;
        int cnt = 0;
        #pragma unroll
        for (int s = 0; s < 16; ++s) {
            ushort_t v = Hraw[(lane * 16 + s) * 2];
            int e = (v >> 7) & 0xFF;
            cnt += (((e >= 90) && (e <= 140)) || (v == 0)) ? 1 : 0;
        }
        #pragma unroll
        for (int off = 32; off; off >>= 1) cnt += __shfl_down(cnt, off);
        if (lane == 0) *flag = (cnt < 768) ? 1 : 0;
    }

    // ---- mask pack (all blocks): 4 int4 per thread ----
    {
        const int lane = tid & 63;
        #pragma unroll
        for (int kk = 0; kk < 4; ++kk) {
            const int flat4 = (bx * 4 + kk) * 256 + tid;   // index in units of int4
            const int row   = flat4 >> 10;                 // (flat4*4) >> 12
            const int col0  = (flat4 << 2) & 4095;
            const int4v a   = ((const int4v*)A)[flat4];
            unsigned nib = 0;
            #pragma unroll
            for (int j = 0; j < 4; ++j)
                nib |= ((a[j] != 0) || (row == col0 + j)) ? (1u << j) : 0u;
            unsigned long long v = (unsigned long long)nib << ((lane & 15) * 4);
            v |= __shfl_xor(v, 1);
            v |= __shfl_xor(v, 2);
            v |= __shfl_xor(v, 4);
            v |= __shfl_xor(v, 8);
            if ((lane & 15) == 0) P[flat4 >> 4] = v;
        }
    }

    // ---- zero sl/sr (blocks 64..95): 8192 threads x one float4 ----
    if (bx >= 64 && bx < 96) {
        const int idx = (bx - 64) * 256 + tid;        // 0..8191
        float4v z;
        #pragma unroll
        for (int e = 0; e < 4; ++e) z[e] = 0.f;
        if (idx < 4096) ((float4v*)sl)[idx] = z;
        else            ((float4v*)sr)[idx - 4096] = z;
    }

    // ---- W transpose (blocks 0..63) ----
    if (bx < 64) {
        // block-local dtype detection (same 1024 samples as the global flag)
        int cnt = 0;
        #pragma unroll
        for (int s = 0; s < 4; ++s) {
            ushort_t v = Hraw[(tid * 4 + s) * 2];
            int e = (v >> 7) & 0xFF;
            cnt += (((e >= 90) && (e <= 140)) || (v == 0)) ? 1 : 0;
        }
        #pragma unroll
        for (int off = 32; off; off >>= 1) cnt += __shfl_down(cnt, off);
        if ((tid & 63) == 0) dcnt[tid >> 6] = cnt;
        __syncthreads();
        const int f32 = (dcnt[0] + dcnt[1] + dcnt[2] + dcnt[3]) < 768;

        const int ti = bx >> 3, tj = bx & 7;
        const int r = tid >> 2, c2 = tid & 3;
        const size_t eo = (size_t)(ti * 64 + r) * KDIM + tj * 64 + c2 * 16;
        if (f32) {
            const float4v* src = (const float4v*)((const float*)W + eo);
            float4v f0 = src[0], f1 = src[1], f2 = src[2], f3 = src[3];
            #pragma unroll
            for (int e = 0; e < 4; ++e) {
                lt[r][c2 * 16 +  0 + e] = f2bf_rne(f0[e]);
                lt[r][c2 * 16 +  4 + e] = f2bf_rne(f1[e]);
                lt[r][c2 * 16 +  8 + e] = f2bf_rne(f2[e]);
                lt[r][c2 * 16 + 12 + e] = f2bf_rne(f3[e]);
            }
        } else {
            const short8* src = (const short8*)((const ushort_t*)W + eo);
            short8 v0 = src[0];
            short8 v1 = src[1];
            *(short8*)&lt[r][c2 * 16]     = v0;
            *(short8*)&lt[r][c2 * 16 + 8] = v1;
        }
        __syncthreads();
        #pragma unroll
        for (int itr = 0; itr < 2; ++itr) {
            int idx = itr * 256 + tid;
            int n = idx >> 3, c = idx & 7;
            short8 vv;
            #pragma unroll
            for (int e = 0; e < 8; ++e) vv[e] = (short)lt[c * 8 + e][n];
            *(short8*)(WT + (size_t)(tj * 64 + n) * KDIM + ti * 64 + c * 8) = vv;
        }
    }
}

// ---------------------------------------------------------------------------
// Kernel 2 v19 (unchanged): WhT = (H @ W)^T with LDS-staged B panel + fused
// slsr partials.
// ---------------------------------------------------------------------------
__global__ __launch_bounds__(256) void gemm_wht_dual_k(const void* __restrict__ H,
                                                       const ushort_t* __restrict__ WT,
                                                       ushort_t* __restrict__ WhT,
                                                       const int* __restrict__ flag,
                                                       const void* __restrict__ al,
                                                       const void* __restrict__ ar,
                                                       float* __restrict__ sl,
                                                       float* __restrict__ sr)
{
    __shared__ ushort_t Bs[64 * KDIM];   // 64 KB staged B panel (slot-swizzled)
    __shared__ ushort_t lt[64][72];
    const int f32 = *flag;
    const int tid  = threadIdx.x;
    const int lane = tid & 63;
    const int wid  = tid >> 6;
    const int quad = lane >> 4;
    const int l15  = lane & 15;
    const int bm = blockIdx.x & 63, bn = blockIdx.x >> 6;
    const int i0 = bm * 64, n0 = bn * 64;

    // ---- stage B panel: wave wid stages rows wid*16 .. +15, 1 call/row ----
    #pragma unroll
    for (int rr = 0; rr < 16; ++rr) {
        const int n = wid * 16 + rr;
        const ushort_t* src = WT + (size_t)(n0 + n) * KDIM + (size_t)((lane ^ (n & 3)) * 8);
        __builtin_amdgcn_global_load_lds(
            (const __attribute__((address_space(1))) void*)src,
            (__attribute__((address_space(3))) void*)(Bs + n * KDIM), 16, 0, 0);
    }
    asm volatile("s_waitcnt vmcnt(0)" ::: "memory");
    __syncthreads();

    const size_t aoff = (size_t)(i0 + wid * 16 + l15) * KDIM + quad * 8;

    float4v acc0, acc1, acc2, acc3;
    #pragma unroll
    for (int e = 0; e < 4; ++e) { acc0[e] = 0.f; acc1[e] = 0.f; acc2[e] = 0.f; acc3[e] = 0.f; }

    const int sx = l15 & 3;   // read-slot XOR (matches stage pre-swizzle)

    #pragma unroll 4
    for (int k8 = 0; k8 < 64; k8 += 4) {
        short8 a;
        if (f32) {
            const float4v* fp = (const float4v*)((const float*)H + aoff + (size_t)k8 * 8);
            float4v x0 = fp[0], x1 = fp[1];
            #pragma unroll
            for (int e = 0; e < 4; ++e) {
                a[e]     = (short)f2bf_rne(x0[e]);
                a[4 + e] = (short)f2bf_rne(x1[e]);
            }
        } else {
            a = *(const short8*)((const ushort_t*)H + aoff + (size_t)k8 * 8);
        }
        const int s = (quad + k8) ^ sx;
        short8 b0 = *(const short8*)(Bs + ( 0 + l15) * KDIM + s * 8);
        short8 b1 = *(const short8*)(Bs + (16 + l15) * KDIM + s * 8);
        short8 b2 = *(const short8*)(Bs + (32 + l15) * KDIM + s * 8);
        short8 b3 = *(const short8*)(Bs + (48 + l15) * KDIM + s * 8);
        acc0 = __builtin_amdgcn_mfma_f32_16x16x32_bf16(a, b0, acc0, 0, 0, 0);
        acc1 = __builtin_amdgcn_mfma_f32_16x16x32_bf16(a, b1, acc1, 0, 0, 0);
        acc2 = __builtin_amdgcn_mfma_f32_16x16x32_bf16(a, b2, acc2, 0, 0, 0);
        acc3 = __builtin_amdgcn_mfma_f32_16x16x32_bf16(a, b3, acc3, 0, 0, 0);
    }

    #pragma unroll
    for (int r = 0; r < 4; ++r) {
        int m = wid * 16 + quad * 4 + r;
        lt[ 0 + l15][m] = f2bf_rne(acc0[r]);
        lt[16 + l15][m] = f2bf_rne(acc1[r]);
        lt[32 + l15][m] = f2bf_rne(acc2[r]);
        lt[48 + l15][m] = f2bf_rne(acc3[r]);
    }
    __syncthreads();
    #pragma unroll
    for (int itr = 0; itr < 2; ++itr) {
        int idx = itr * 256 + tid;
        int n = idx >> 3, c = idx & 7;
        short8 v = *(const short8*)&lt[n][c * 8];
        *(short8*)(WhT + (size_t)(n0 + n) * N_NODES + i0 + c * 8) = v;
    }

    // ---- fused slsr partials over this block's 64 d-values ----
    {
        const int h2 = n0 >> 7;          // head
        const int d0 = n0 & 127;         // d offset within head
        const int m  = tid >> 2;         // output row = i0 + m
        const int part = tid & 3;
        float psl = 0.f, psr = 0.f;
        #pragma unroll
        for (int k = 0; k < 16; ++k) {
            int n = part * 16 + k;
            float wv = bf2f(lt[n][m]);
            float av = f32 ? ((const float*)al)[h2 * DK + d0 + n]
                           : bf2f(((const ushort_t*)al)[h2 * DK + d0 + n]);
            float bv = f32 ? ((const float*)ar)[h2 * DK + d0 + n]
                           : bf2f(((const ushort_t*)ar)[h2 * DK + d0 + n]);
            psl += wv * av;
            psr += wv * bv;
        }
        psl += __shfl_down(psl, 2); psl += __shfl_down(psl, 1);
        psr += __shfl_down(psr, 2); psr += __shfl_down(psr, 1);
        if (part == 0) {
            atomicAdd(&sl[h2 * N_NODES + i0 + m], psl);
            atomicAdd(&sr[h2 * N_NODES + i0 + m], psr);
        }
    }
}

// ---------------------------------------------------------------------------
// Kernel 3 v20 (reverted from v21 — VGPR spill at the (1024,4) 128-cap:
// WRITE_SIZE 8192->14080 KB scratch signature, attn 41.8->57.5us.  The
// 2-row-group variant cannot fit this occupancy point; v20 is the proven
// optimum of this structure).  Big-window / trivial-sync attention:
// window = 256j x 128d (64 KB), 2 buffers, ONE __syncthreads per window,
// register-prefetched global masks, full-32-slot XOR involution
// slot = p ^ (d&31) (conflicts 393K), setprio around MFMA cluster.
// ---------------------------------------------------------------------------
__global__ __launch_bounds__(1024, 4) void attn_full_k(const ushort_t* __restrict__ WhT,
                                                       const unsigned* __restrict__ Apack,
                                                       const float* __restrict__ sl,
                                                       const float* __restrict__ sr,
                                                       void* __restrict__ out,
                                                       const int* __restrict__ flag)
{
    __shared__ char smem[147456] __attribute__((aligned(16)));
    ushort_t* vbuf = (ushort_t*)smem;                 // 2 x 64 KB windows
    float*    srs  = (float*)(smem + 131072);         // 4096 f32, 16 KB

    const int f32  = *flag;
    const int tid  = threadIdx.x;
    const int lane = tid & 63;
    const int wid  = tid >> 6;               // 0..15
    const int wq   = wid & 3;                // row group: rows wq*16..+15
    const int js   = wid >> 2;               // j substream 0..3 (64j of the 256j window)
    const int quad = lane >> 4;
    const int l15  = lane & 15;
    const int bx   = blockIdx.x;
    const int h    = bx & 3;                 // head
    const int i0   = (bx >> 2) << 6;         // 64-row tile

    const float C1 = 1.44269504f;             // log2(e)

    for (int j = tid; j < 4096; j += 1024) srs[j] = sr[h * N_NODES + j] * C1;
    const int myrow = wq * 16 + l15;
    const float slv = sl[h * N_NODES + i0 + myrow] * C1;
    const unsigned* mrow = Apack + (size_t)(i0 + myrow) * 128;   // this row's mask words
    __syncthreads();    // srs visible

    float4v acc[8];
    #pragma unroll
    for (int nt = 0; nt < 8; ++nt)
        #pragma unroll
        for (int e = 0; e < 4; ++e) acc[nt][e] = 0.f;
    float4v accden;
    #pragma unroll
    for (int e = 0; e < 4; ++e) accden[e] = 0.f;

    short8 ones;
    #pragma unroll
    for (int e = 0; e < 8; ++e) ones[e] = (short)0x3F80;   // bf16 1.0

    // DMA: window = 256j x 128d (64 KB), row = 512 B (32 slots of 16 B).
    // Wave wid stages d-rows [wid*8, +8) via 4 calls of 2 rows.
    const int rrow  = lane >> 5;             // 0..1
    const int s32   = lane & 31;
    const int dbase = wid * 8;

    #define DMA_WIN(BUF, W)                                                            \
        { _Pragma("unroll")                                                            \
          for (int q_ = 0; q_ < 4; ++q_) {                                             \
            const int d_  = dbase + q_ * 2 + rrow;                                     \
            const int ch_ = s32 ^ (d_ & 31);                                           \
            const ushort_t* g_ = WhT + (size_t)(h * DK + d_) * N_NODES                 \
                                      + (size_t)(W) * 256 + (size_t)ch_ * 8;           \
            __builtin_amdgcn_global_load_lds(                                          \
                (const __attribute__((address_space(1))) void*)g_,                     \
                (__attribute__((address_space(3))) void*)(vbuf + (BUF) * 32768         \
                                                         + wid * 2048 + q_ * 512),     \
                16, 0, 0);                                                             \
          } }

    unsigned wa0 = mrow[js * 2 + 0];
    unsigned wa1 = mrow[js * 2 + 1];
    DMA_WIN(0, 0)

    #pragma unroll 1
    for (int w = 0; w < 16; ++w) {
        __syncthreads();                     // drains vmcnt: window w + masks landed
        unsigned wa0n = wa0, wa1n = wa1;
        if (w < 15) {
            wa0n = mrow[(w + 1) * 8 + js * 2 + 0];
            wa1n = mrow[(w + 1) * 8 + js * 2 + 1];
            DMA_WIN((w + 1) & 1, w + 1)
        }

        const float4v a0 = *(const float4v*)&srs[w * 256 + js * 64 + quad * 8];
        const float4v a1 = *(const float4v*)&srs[w * 256 + js * 64 + quad * 8 + 4];
        const float4v b0 = *(const float4v*)&srs[w * 256 + js * 64 + 32 + quad * 8];
        const float4v b1 = *(const float4v*)&srs[w * 256 + js * 64 + 32 + quad * 8 + 4];

        short8 pf0, pf1;
        #pragma unroll
        for (int jj = 0; jj < 8; ++jj) {
            const int bit = quad * 8 + jj;
            float x = slv + ((jj < 4) ? a0[jj] : a1[jj - 4]);   // both *C1
            float t = fmaxf(x, x * 0.2f);
            t = ((wa0 >> bit) & 1u) ? t : -1e30f;
            pf0[jj] = (short)(ushort_t)(__float_as_uint(__builtin_amdgcn_exp2f(t)) >> 16);
            float y = slv + ((jj < 4) ? b0[jj] : b1[jj - 4]);
            float u = fmaxf(y, y * 0.2f);
            u = ((wa1 >> bit) & 1u) ? u : -1e30f;
            pf1[jj] = (short)(ushort_t)(__float_as_uint(__builtin_amdgcn_exp2f(u)) >> 16);
        }

        const ushort_t* vB = vbuf + (w & 1) * 32768;
        __builtin_amdgcn_s_setprio(1);
        #pragma unroll
        for (int nt = 0; nt < 8; ++nt) {
            const int roff  = (nt * 16 + l15) * 256;            // ushorts
            const int dlow  = (nt & 1) * 16 + l15;              // d&31 of this row
            const int slot0 = (js * 8 + 0 + quad) ^ dlow;
            const int slot1 = (js * 8 + 4 + quad) ^ dlow;
            short8 bv0 = *(const short8*)(vB + roff + slot0 * 8);
            short8 bv1 = *(const short8*)(vB + roff + slot1 * 8);
            acc[nt] = __builtin_amdgcn_mfma_f32_16x16x32_bf16(pf0, bv0, acc[nt], 0, 0, 0);
            acc[nt] = __builtin_amdgcn_mfma_f32_16x16x32_bf16(pf1, bv1, acc[nt], 0, 0, 0);
        }
        accden = __builtin_amdgcn_mfma_f32_16x16x32_bf16(pf0, ones, accden, 0, 0, 0);
        accden = __builtin_amdgcn_mfma_f32_16x16x32_bf16(pf1, ones, accden, 0, 0, 0);
        __builtin_amdgcn_s_setprio(0);

        wa0 = wa0n; wa1 = wa1n;
    }
    #undef DMA_WIN

    // ---- epilogue: reduce js 1..3 into js 0, normalize, elu, store ----
    float* red  = (float*)smem;                       // [3][4wq][16][128] f32 = 96 KB
    float* lsum = (float*)(smem + 98304);             // [4js][64] f32
    __syncthreads();                                   // all DMAs drained; reads done

    if (js != 0) {
        float* rp = red + (size_t)((js - 1) * 4 + wq) * 2048;
        #pragma unroll
        for (int nt = 0; nt < 8; ++nt)
            #pragma unroll
            for (int r = 0; r < 4; ++r)
                rp[(quad * 4 + r) * 128 + nt * 16 + l15] = acc[nt][r];
        if (l15 == 0) {
            #pragma unroll
            for (int r = 0; r < 4; ++r)
                lsum[js * 64 + wq * 16 + quad * 4 + r] = accden[r];
        }
    }
    __syncthreads();
    if (js == 0) {
        float rinv[4];
        #pragma unroll
        for (int r = 0; r < 4; ++r) {
            const int rowo = wq * 16 + quad * 4 + r;
            float den = accden[r] + lsum[64 + rowo] + lsum[128 + rowo] + lsum[192 + rowo];
            rinv[r] = 1.0f / fmaxf(den, 1e-37f);
        }
        #pragma unroll
        for (int nt = 0; nt < 8; ++nt)
            #pragma unroll
            for (int r = 0; r < 4; ++r) {
                const int ri = (quad * 4 + r) * 128 + nt * 16 + l15;
                float v = (acc[nt][r]
                           + red[(size_t)(0 * 4 + wq) * 2048 + ri]
                           + red[(size_t)(1 * 4 + wq) * 2048 + ri]
                           + red[(size_t)(2 * 4 + wq) * 2048 + ri]) * rinv[r];
                float e = __builtin_amdgcn_exp2f(v * C1) - 1.0f;
                float o = (v > 0.f) ? v : e;
                const size_t oidx = (size_t)(i0 + wq * 16 + quad * 4 + r) * ODIM
                                  + h * DK + nt * 16 + l15;
                if (f32) ((float*)out)[oidx] = o;
                else     ((ushort_t*)out)[oidx] = f2bf_rne(o);
            }
    }
}

// ---------------------------------------------------------------------------
extern "C" void kernel_launch(void* const* d_in, const int* in_sizes, int n_in,
                              void* d_out, int out_size, void* d_ws, size_t ws_size,
                              hipStream_t stream)
{
    const void* H  = d_in[0];
    const int*  A  = (const int*)d_in[1];
    const void* W  = d_in[2];
    const void* al = d_in[3];
    const void* ar = d_in[4];

    if (ws_size < (7u << 20)) return;

    char* ws = (char*)d_ws;
    ushort_t* WhT   = (ushort_t*)ws;                                    // 4 MB
    unsigned long long* Apack = (unsigned long long*)(ws + (4u << 20)); // 2 MB
    ushort_t* WT    = (ushort_t*)(ws + (6u << 20));                     // 512 KB
    float*    sl    = (float*)(ws + (6u << 20) + (512u << 10));         // 64 KB
    float*    sr    = (float*)(ws + (6u << 20) + (576u << 10));         // 64 KB
    int*      flag  = (int*)(ws + (6u << 20) + (640u << 10));           // 4 B

    pack_mask_k    <<<4096,  256, 0, stream>>>(A, Apack, (const ushort_t*)H, flag,
                                               W, WT, sl, sr);
    gemm_wht_dual_k<<<512,   256, 0, stream>>>(H, WT, WhT, flag, al, ar, sl, sr);
    attn_full_k    <<<256,  1024, 0, stream>>>(WhT, (const unsigned*)Apack, sl, sr,
                                               (void*)d_out, flag);
}